// Round 2
// baseline (884.150 us; speedup 1.0000x reference)
//
#include <hip/hip_runtime.h>
#include <hip/hip_bf16.h>
#include <math.h>

#define N_NODES 100000
#define N_EDGES 1600000
#define F_IN 256
#define DIM 32
#define NC 40

// ---------------- degree ----------------
__global__ void deg_kernel(const int* __restrict__ dst, float* __restrict__ deg) {
    int i = blockIdx.x * blockDim.x + threadIdx.x;
    if (i < N_EDGES) atomicAdd(&deg[dst[i]], 1.0f);
}

// ---------------- layer-1 projection: P1 = x@W1l, R1 = x@W1r ----------------
// One 64-lane wave per node: lanes 0..31 -> W1l (P1), lanes 32..63 -> W1r (R1).
__global__ void proj1_kernel(const float* __restrict__ x,
                             const float* __restrict__ W1l,
                             const float* __restrict__ W1r,
                             float* __restrict__ P1,
                             float* __restrict__ R1) {
    int node = blockIdx.x * 4 + (threadIdx.x >> 6);
    int lane = threadIdx.x & 63;
    int j = lane & 31;
    __shared__ float xs[4][F_IN];
    float* xsr = xs[threadIdx.x >> 6];
    if (node < N_NODES) {
        const float* xrow = x + (size_t)node * F_IN;
        for (int k = lane; k < F_IN; k += 64) xsr[k] = xrow[k];
    }
    __syncthreads();
    if (node >= N_NODES) return;
    const float* __restrict__ W = (lane < 32) ? W1l : W1r;
    float acc = 0.f;
#pragma unroll 8
    for (int k = 0; k < F_IN; ++k)
        acc += xsr[k] * W[k * DIM + j];
    if (lane < 32) P1[(size_t)node * DIM + j] = acc;
    else           R1[(size_t)node * DIM + j] = acc;
}

// ---------------- scatter-add of 32-dim features over edges ----------------
__global__ void scatter_kernel(const int* __restrict__ src,
                               const int* __restrict__ dst,
                               const float* __restrict__ feat,
                               float* __restrict__ agg) {
    int id = blockIdx.x * blockDim.x + threadIdx.x;   // < E*32 = 51.2M
    if (id >= N_EDGES * DIM) return;
    int e = id >> 5;
    int j = id & 31;
    int s = src[e];
    int d = dst[e];
    atomicAdd(&agg[(size_t)d * DIM + j], feat[(size_t)s * DIM + j]);
}

// ---------------- h = relu(agg*inv_deg + R1 + b1) ----------------
__global__ void h_kernel(const float* __restrict__ agg1,
                         const float* __restrict__ R1,
                         const float* __restrict__ b1,
                         const float* __restrict__ deg,
                         float* __restrict__ h) {
    int id = blockIdx.x * blockDim.x + threadIdx.x;   // < N*32
    if (id >= N_NODES * DIM) return;
    int n = id >> 5, j = id & 31;
    float inv = 1.0f / fmaxf(deg[n], 1.0f);
    float v = fmaf(agg1[id], inv, R1[id]) + b1[j];
    h[id] = v > 0.f ? v : 0.f;
}

// ---------------- out = log_softmax(agg2*inv @ W2l + h @ W2r + b2) ----------------
// One wave per node; lane j < 40 owns class j.
__global__ void out_kernel(const float* __restrict__ agg2,
                           const float* __restrict__ h,
                           const float* __restrict__ W2l,
                           const float* __restrict__ W2r,
                           const float* __restrict__ b2,
                           const float* __restrict__ deg,
                           float* __restrict__ out) {
    int node = blockIdx.x * 4 + (threadIdx.x >> 6);
    if (node >= N_NODES) return;
    int lane = threadIdx.x & 63;
    float inv = 1.0f / fmaxf(deg[node], 1.0f);
    float y = -INFINITY;
    if (lane < NC) {
        float acc = b2[lane];
        const float* ar = agg2 + (size_t)node * DIM;
        const float* hr = h + (size_t)node * DIM;
#pragma unroll
        for (int k = 0; k < DIM; ++k) {
            acc = fmaf(ar[k] * inv, W2l[k * NC + lane], acc);
            acc = fmaf(hr[k],       W2r[k * NC + lane], acc);
        }
        y = acc;
    }
    float m = y;
    for (int off = 32; off; off >>= 1) m = fmaxf(m, __shfl_xor(m, off, 64));
    float ex = (lane < NC) ? __expf(y - m) : 0.f;
    float s = ex;
    for (int off = 32; off; off >>= 1) s += __shfl_xor(s, off, 64);
    if (lane < NC) out[(size_t)node * NC + lane] = y - m - __logf(s);
}

extern "C" void kernel_launch(void* const* d_in, const int* in_sizes, int n_in,
                              void* d_out, int out_size, void* d_ws, size_t ws_size,
                              hipStream_t stream) {
    const float* x   = (const float*)d_in[0];
    const int*   ei  = (const int*)d_in[1];   // harness delivers integer inputs as int32
    const float* W1l = (const float*)d_in[2];
    const float* W1r = (const float*)d_in[3];
    const float* b1  = (const float*)d_in[4];
    const float* W2l = (const float*)d_in[5];
    const float* W2r = (const float*)d_in[6];
    const float* b2  = (const float*)d_in[7];
    float* out = (float*)d_out;

    const int* src = ei;
    const int* dst = ei + N_EDGES;

    // workspace layout (floats)
    float* ws   = (float*)d_ws;
    float* deg  = ws;                         // N (rounded up to 102400)
    float* P1   = ws + 102400;                // N*32
    float* R1   = P1 + (size_t)N_NODES * DIM; // N*32
    float* h    = R1 + (size_t)N_NODES * DIM; // N*32
    float* agg  = h  + (size_t)N_NODES * DIM; // N*32 (reused for both layers)

    hipMemsetAsync(deg, 0, sizeof(float) * N_NODES, stream);
    hipMemsetAsync(agg, 0, sizeof(float) * (size_t)N_NODES * DIM, stream);

    deg_kernel<<<(N_EDGES + 255) / 256, 256, 0, stream>>>(dst, deg);
    proj1_kernel<<<(N_NODES + 3) / 4, 256, 0, stream>>>(x, W1l, W1r, P1, R1);
    scatter_kernel<<<(N_EDGES * DIM) / 256, 256, 0, stream>>>(src, dst, P1, agg);
    h_kernel<<<(N_NODES * DIM + 255) / 256, 256, 0, stream>>>(agg, R1, b1, deg, h);

    hipMemsetAsync(agg, 0, sizeof(float) * (size_t)N_NODES * DIM, stream);
    scatter_kernel<<<(N_EDGES * DIM) / 256, 256, 0, stream>>>(src, dst, h, agg);
    out_kernel<<<(N_NODES + 3) / 4, 256, 0, stream>>>(agg, h, W2l, W2r, b2, deg, out);
}

// Round 3
// 654.252 us; speedup vs baseline: 1.3514x; 1.3514x over previous
//
#include <hip/hip_runtime.h>
#include <hip/hip_bf16.h>
#include <math.h>

#define N_NODES 100000
#define N_EDGES 1600000
#define F_IN 256
#define DIM 32
#define NC 40

// ================= CSR construction =================

__global__ void deg_kernel(const int* __restrict__ dst, int* __restrict__ degi) {
    int i = blockIdx.x * blockDim.x + threadIdx.x;
    if (i < N_EDGES) atomicAdd(&degi[dst[i]], 1);
}

// Allocate contiguous (but not node-ordered) CSR row segments:
// wave-level inclusive scan of degrees + one global-cursor atomic per wave.
__global__ void alloc_kernel(const int* __restrict__ degi,
                             int* __restrict__ rowstart,
                             int* __restrict__ cursor,
                             int* __restrict__ counter) {
    int i = blockIdx.x * blockDim.x + threadIdx.x;
    int lane = threadIdx.x & 63;
    int v = (i < N_NODES) ? degi[i] : 0;
    int s = v;
#pragma unroll
    for (int off = 1; off < 64; off <<= 1) {
        int t = __shfl_up(s, off, 64);
        if (lane >= off) s += t;
    }
    int base = 0;
    if (lane == 63) base = atomicAdd(counter, s);
    base = __shfl(base, 63, 64);
    if (i < N_NODES) {
        int st = base + s - v;
        rowstart[i] = st;
        cursor[i] = st;
    }
}

__global__ void fill_kernel(const int* __restrict__ src,
                            const int* __restrict__ dst,
                            int* __restrict__ cursor,
                            int* __restrict__ csr) {
    int e = blockIdx.x * blockDim.x + threadIdx.x;
    if (e >= N_EDGES) return;
    int d = dst[e];
    int pos = atomicAdd(&cursor[d], 1);
    csr[pos] = src[e];
}

// ================= layer-1 projection (register-tiled GEMM) =================
// C-tile: 256 nodes x 64 cols per block (cols 0-31 -> P1 = x@W1l, 32-63 -> R1 = x@W1r)
// thread: 8 nodes x 8 cols outer-product from LDS.
#define PT_NODES 256
#define PT_KT 16

__global__ __launch_bounds__(256)
void proj1_tiled(const float* __restrict__ x,
                 const float* __restrict__ W1l,
                 const float* __restrict__ W1r,
                 float* __restrict__ P1,
                 float* __restrict__ R1) {
    __shared__ float xs[PT_KT][PT_NODES];  // 16 KB
    __shared__ float ws[PT_KT][64];        // 4 KB
    int t = threadIdx.x;
    int ng = t >> 3;   // 0..31 node group
    int cg = t & 7;    // 0..7 col group
    int n0 = blockIdx.x * PT_NODES;

    float acc[8][8];
#pragma unroll
    for (int i = 0; i < 8; ++i)
#pragma unroll
        for (int j = 0; j < 8; ++j) acc[i][j] = 0.f;

    int ldnode = n0 + t; if (ldnode >= N_NODES) ldnode = N_NODES - 1;
    const float* xrow = x + (size_t)ldnode * F_IN;
    int wr = t >> 4;           // 0..15 (k within tile)
    int wc = (t & 15) * 4;     // 0..60

    for (int k0 = 0; k0 < F_IN; k0 += PT_KT) {
        // stage x: thread t loads 16 floats of node (n0+t), transposed into xs[kk][t]
        float4 a = *(const float4*)&xrow[k0];
        float4 b = *(const float4*)&xrow[k0 + 4];
        float4 c = *(const float4*)&xrow[k0 + 8];
        float4 d = *(const float4*)&xrow[k0 + 12];
        xs[0][t] = a.x;  xs[1][t] = a.y;  xs[2][t] = a.z;  xs[3][t] = a.w;
        xs[4][t] = b.x;  xs[5][t] = b.y;  xs[6][t] = b.z;  xs[7][t] = b.w;
        xs[8][t] = c.x;  xs[9][t] = c.y;  xs[10][t] = c.z; xs[11][t] = c.w;
        xs[12][t] = d.x; xs[13][t] = d.y; xs[14][t] = d.z; xs[15][t] = d.w;
        // stage W: ws[r][c] = (c<32 ? W1l : W1r)[k0+r][c%32]
        float4 w = (wc < 32) ? *(const float4*)&W1l[(size_t)(k0 + wr) * DIM + wc]
                             : *(const float4*)&W1r[(size_t)(k0 + wr) * DIM + (wc - 32)];
        *(float4*)&ws[wr][wc] = w;
        __syncthreads();
#pragma unroll
        for (int kk = 0; kk < PT_KT; ++kk) {
            float xv[8], wv[8];
            *(float4*)&xv[0] = *(const float4*)&xs[kk][ng * 8];
            *(float4*)&xv[4] = *(const float4*)&xs[kk][ng * 8 + 4];
            *(float4*)&wv[0] = *(const float4*)&ws[kk][cg * 8];
            *(float4*)&wv[4] = *(const float4*)&ws[kk][cg * 8 + 4];
#pragma unroll
            for (int i = 0; i < 8; ++i)
#pragma unroll
                for (int j = 0; j < 8; ++j)
                    acc[i][j] = fmaf(xv[i], wv[j], acc[i][j]);
        }
        __syncthreads();
    }

    bool isP = (cg < 4);
    float* dbuf = isP ? P1 : R1;
    int c0 = (isP ? cg : cg - 4) * 8;
    int nb = n0 + ng * 8;
#pragma unroll
    for (int i = 0; i < 8; ++i) {
        int n = nb + i;
        if (n < N_NODES) {
            *(float4*)&dbuf[(size_t)n * DIM + c0]     = *(float4*)&acc[i][0];
            *(float4*)&dbuf[(size_t)n * DIM + c0 + 4] = *(float4*)&acc[i][4];
        }
    }
}

// ================= layer-1 aggregate + relu =================
// one wave per node; half-wave per edge (32 dims contiguous = 128B gather)
__global__ void agg1_h_kernel(const int* __restrict__ rowstart,
                              const int* __restrict__ degi,
                              const int* __restrict__ csr,
                              const float* __restrict__ P1,
                              const float* __restrict__ R1,
                              const float* __restrict__ b1,
                              float* __restrict__ h) {
    int node = blockIdx.x * 4 + (threadIdx.x >> 6);
    if (node >= N_NODES) return;
    int lane = threadIdx.x & 63;
    int j = lane & 31;
    int half = lane >> 5;
    int rs = rowstart[node];
    int dg = degi[node];
    int re = rs + dg;
    float acc = 0.f;
    for (int e = rs + half; e < re; e += 2) {
        int s = csr[e];
        acc += P1[(size_t)s * DIM + j];
    }
    acc += __shfl_xor(acc, 32, 64);
    if (lane < 32) {
        float inv = 1.0f / (float)max(dg, 1);
        float v = fmaf(acc, inv, R1[(size_t)node * DIM + j] + b1[j]);
        h[(size_t)node * DIM + j] = v > 0.f ? v : 0.f;
    }
}

// ================= layer-2 aggregate + linear + log_softmax =================
__global__ void agg2_out_kernel(const int* __restrict__ rowstart,
                                const int* __restrict__ degi,
                                const int* __restrict__ csr,
                                const float* __restrict__ h,
                                const float* __restrict__ W2l,
                                const float* __restrict__ W2r,
                                const float* __restrict__ b2,
                                float* __restrict__ out) {
    __shared__ float sW2l[DIM * NC];
    __shared__ float sW2r[DIM * NC];
    __shared__ float sb2[NC];
    for (int i = threadIdx.x; i < DIM * NC; i += 256) {
        sW2l[i] = W2l[i];
        sW2r[i] = W2r[i];
    }
    if (threadIdx.x < NC) sb2[threadIdx.x] = b2[threadIdx.x];
    __syncthreads();

    int node = blockIdx.x * 4 + (threadIdx.x >> 6);
    if (node >= N_NODES) return;
    int lane = threadIdx.x & 63;
    int j = lane & 31;
    int half = lane >> 5;
    int rs = rowstart[node];
    int dg = degi[node];
    int re = rs + dg;
    float acc = 0.f;
    for (int e = rs + half; e < re; e += 2) {
        int s = csr[e];
        acc += h[(size_t)s * DIM + j];
    }
    acc += __shfl_xor(acc, 32, 64);        // both halves now hold full sum for dim j
    float inv = 1.0f / (float)max(dg, 1);
    float a2 = acc * inv;                  // lane j (and j+32) holds agg2[node][j]
    float hv = h[(size_t)node * DIM + j];  // root features

    float y = -INFINITY;
    if (lane < NC) {
        float s = sb2[lane];
#pragma unroll
        for (int k = 0; k < DIM; ++k) {
            float a2k = __shfl(a2, k, 64);
            float hk  = __shfl(hv, k, 64);
            s = fmaf(a2k, sW2l[k * NC + lane], s);
            s = fmaf(hk,  sW2r[k * NC + lane], s);
        }
        y = s;
    }
    float m = y;
#pragma unroll
    for (int off = 32; off; off >>= 1) m = fmaxf(m, __shfl_xor(m, off, 64));
    float ex = (lane < NC) ? __expf(y - m) : 0.f;
    float sum = ex;
#pragma unroll
    for (int off = 32; off; off >>= 1) sum += __shfl_xor(sum, off, 64);
    if (lane < NC) out[(size_t)node * NC + lane] = y - m - __logf(sum);
}

// ================= launch =================
extern "C" void kernel_launch(void* const* d_in, const int* in_sizes, int n_in,
                              void* d_out, int out_size, void* d_ws, size_t ws_size,
                              hipStream_t stream) {
    const float* x   = (const float*)d_in[0];
    const int*   ei  = (const int*)d_in[1];   // int32 [2, E]
    const float* W1l = (const float*)d_in[2];
    const float* W1r = (const float*)d_in[3];
    const float* b1  = (const float*)d_in[4];
    const float* W2l = (const float*)d_in[5];
    const float* W2r = (const float*)d_in[6];
    const float* b2  = (const float*)d_in[7];
    float* out = (float*)d_out;

    const int* src = ei;
    const int* dst = ei + N_EDGES;

    // workspace layout
    char* ws = (char*)d_ws;
    int*   degi     = (int*)ws;                 ws += sizeof(int) * 102400;
    int*   rowstart = (int*)ws;                 ws += sizeof(int) * 102400;
    int*   cursor   = (int*)ws;                 ws += sizeof(int) * 102400;
    int*   counter  = (int*)ws;                 ws += sizeof(int) * 256;
    int*   csr      = (int*)ws;                 ws += sizeof(int) * N_EDGES;
    float* P1       = (float*)ws;               ws += sizeof(float) * N_NODES * DIM;
    float* R1       = (float*)ws;               ws += sizeof(float) * N_NODES * DIM;
    float* h        = (float*)ws;               ws += sizeof(float) * N_NODES * DIM;

    hipMemsetAsync(degi, 0, sizeof(int) * 102400, stream);
    hipMemsetAsync(counter, 0, sizeof(int) * 256, stream);

    deg_kernel<<<(N_EDGES + 255) / 256, 256, 0, stream>>>(dst, degi);
    alloc_kernel<<<(N_NODES + 255) / 256, 256, 0, stream>>>(degi, rowstart, cursor, counter);
    fill_kernel<<<(N_EDGES + 255) / 256, 256, 0, stream>>>(src, dst, cursor, csr);

    proj1_tiled<<<(N_NODES + PT_NODES - 1) / PT_NODES, 256, 0, stream>>>(x, W1l, W1r, P1, R1);

    agg1_h_kernel<<<(N_NODES + 3) / 4, 256, 0, stream>>>(rowstart, degi, csr, P1, R1, b1, h);
    agg2_out_kernel<<<(N_NODES + 3) / 4, 256, 0, stream>>>(rowstart, degi, csr, h, W2l, W2r, b2, out);
}

// Round 4
// 579.167 us; speedup vs baseline: 1.5266x; 1.1296x over previous
//
#include <hip/hip_runtime.h>
#include <hip/hip_bf16.h>
#include <math.h>

#define N_NODES 100000
#define N_EDGES 1600000
#define F_IN 256
#define DIM 32
#define NC 40

// ================= CSR construction =================

__global__ void deg_kernel(const int* __restrict__ dst, int* __restrict__ degi) {
    int i = blockIdx.x * blockDim.x + threadIdx.x;
    if (i < N_EDGES) atomicAdd(&degi[dst[i]], 1);
}

// Allocate contiguous (but not node-ordered) CSR row segments:
// wave-level inclusive scan of degrees + one global-cursor atomic per wave.
__global__ void alloc_kernel(const int* __restrict__ degi,
                             int* __restrict__ rowstart,
                             int* __restrict__ cursor,
                             int* __restrict__ counter) {
    int i = blockIdx.x * blockDim.x + threadIdx.x;
    int lane = threadIdx.x & 63;
    int v = (i < N_NODES) ? degi[i] : 0;
    int s = v;
#pragma unroll
    for (int off = 1; off < 64; off <<= 1) {
        int t = __shfl_up(s, off, 64);
        if (lane >= off) s += t;
    }
    int base = 0;
    if (lane == 63) base = atomicAdd(counter, s);
    base = __shfl(base, 63, 64);
    if (i < N_NODES) {
        int st = base + s - v;
        rowstart[i] = st;
        cursor[i] = st;
    }
}

__global__ void fill_kernel(const int* __restrict__ src,
                            const int* __restrict__ dst,
                            int* __restrict__ cursor,
                            int* __restrict__ csr) {
    int e = blockIdx.x * blockDim.x + threadIdx.x;
    if (e >= N_EDGES) return;
    int d = dst[e];
    int pos = atomicAdd(&cursor[d], 1);
    csr[pos] = src[e];
}

// ================= layer-1 projection (register-tiled GEMM) =================
#define PT_NODES 256
#define PT_KT 16

__global__ __launch_bounds__(256)
void proj1_tiled(const float* __restrict__ x,
                 const float* __restrict__ W1l,
                 const float* __restrict__ W1r,
                 float* __restrict__ P1,
                 float* __restrict__ R1) {
    __shared__ float xs[PT_KT][PT_NODES];  // 16 KB
    __shared__ float ws[PT_KT][64];        // 4 KB
    int t = threadIdx.x;
    int ng = t >> 3;   // 0..31 node group
    int cg = t & 7;    // 0..7 col group
    int n0 = blockIdx.x * PT_NODES;

    float acc[8][8];
#pragma unroll
    for (int i = 0; i < 8; ++i)
#pragma unroll
        for (int j = 0; j < 8; ++j) acc[i][j] = 0.f;

    int ldnode = n0 + t; if (ldnode >= N_NODES) ldnode = N_NODES - 1;
    const float* xrow = x + (size_t)ldnode * F_IN;
    int wr = t >> 4;           // 0..15 (k within tile)
    int wc = (t & 15) * 4;     // 0..60

    for (int k0 = 0; k0 < F_IN; k0 += PT_KT) {
        float4 a = *(const float4*)&xrow[k0];
        float4 b = *(const float4*)&xrow[k0 + 4];
        float4 c = *(const float4*)&xrow[k0 + 8];
        float4 d = *(const float4*)&xrow[k0 + 12];
        xs[0][t] = a.x;  xs[1][t] = a.y;  xs[2][t] = a.z;  xs[3][t] = a.w;
        xs[4][t] = b.x;  xs[5][t] = b.y;  xs[6][t] = b.z;  xs[7][t] = b.w;
        xs[8][t] = c.x;  xs[9][t] = c.y;  xs[10][t] = c.z; xs[11][t] = c.w;
        xs[12][t] = d.x; xs[13][t] = d.y; xs[14][t] = d.z; xs[15][t] = d.w;
        float4 w = (wc < 32) ? *(const float4*)&W1l[(size_t)(k0 + wr) * DIM + wc]
                             : *(const float4*)&W1r[(size_t)(k0 + wr) * DIM + (wc - 32)];
        *(float4*)&ws[wr][wc] = w;
        __syncthreads();
#pragma unroll
        for (int kk = 0; kk < PT_KT; ++kk) {
            float xv[8], wv[8];
            *(float4*)&xv[0] = *(const float4*)&xs[kk][ng * 8];
            *(float4*)&xv[4] = *(const float4*)&xs[kk][ng * 8 + 4];
            *(float4*)&wv[0] = *(const float4*)&ws[kk][cg * 8];
            *(float4*)&wv[4] = *(const float4*)&ws[kk][cg * 8 + 4];
#pragma unroll
            for (int i = 0; i < 8; ++i)
#pragma unroll
                for (int j = 0; j < 8; ++j)
                    acc[i][j] = fmaf(xv[i], wv[j], acc[i][j]);
        }
        __syncthreads();
    }

    bool isP = (cg < 4);
    float* dbuf = isP ? P1 : R1;
    int c0 = (isP ? cg : cg - 4) * 8;
    int nb = n0 + ng * 8;
#pragma unroll
    for (int i = 0; i < 8; ++i) {
        int n = nb + i;
        if (n < N_NODES) {
            *(float4*)&dbuf[(size_t)n * DIM + c0]     = *(float4*)&acc[i][0];
            *(float4*)&dbuf[(size_t)n * DIM + c0 + 4] = *(float4*)&acc[i][4];
        }
    }
}

// ---- gather engine: wave = 8 edge-groups x 8 lanes; lane loads float4 of dims q4..q4+3.
// Returns per-lane float4 holding the FULL edge-sum for dims q4..q4+3 (all lanes).
__device__ __forceinline__ float4 gather_sum(const int* __restrict__ csr,
                                             const float* __restrict__ feat,
                                             int rs, int re, int eg, int q4) {
    float4 acc  = make_float4(0.f, 0.f, 0.f, 0.f);
    float4 acc2 = make_float4(0.f, 0.f, 0.f, 0.f);
    int e = rs + eg;
    for (; e + 8 < re; e += 16) {
        int s0 = csr[e];
        int s1 = csr[e + 8];
        float4 v0 = *(const float4*)&feat[(size_t)s0 * DIM + q4];
        float4 v1 = *(const float4*)&feat[(size_t)s1 * DIM + q4];
        acc.x += v0.x;  acc.y += v0.y;  acc.z += v0.z;  acc.w += v0.w;
        acc2.x += v1.x; acc2.y += v1.y; acc2.z += v1.z; acc2.w += v1.w;
    }
    if (e < re) {
        int s0 = csr[e];
        float4 v0 = *(const float4*)&feat[(size_t)s0 * DIM + q4];
        acc.x += v0.x; acc.y += v0.y; acc.z += v0.z; acc.w += v0.w;
    }
    acc.x += acc2.x; acc.y += acc2.y; acc.z += acc2.z; acc.w += acc2.w;
#pragma unroll
    for (int m = 8; m < 64; m <<= 1) {
        acc.x += __shfl_xor(acc.x, m, 64);
        acc.y += __shfl_xor(acc.y, m, 64);
        acc.z += __shfl_xor(acc.z, m, 64);
        acc.w += __shfl_xor(acc.w, m, 64);
    }
    return acc;
}

// ================= layer-1 aggregate + relu =================
__global__ __launch_bounds__(256)
void agg1_h_kernel(const int* __restrict__ rowstart,
                   const int* __restrict__ degi,
                   const int* __restrict__ csr,
                   const float* __restrict__ P1,
                   const float* __restrict__ R1,
                   const float* __restrict__ b1,
                   float* __restrict__ h) {
    int node = blockIdx.x * 4 + (threadIdx.x >> 6);
    if (node >= N_NODES) return;
    int lane = threadIdx.x & 63;
    int eg = lane >> 3;
    int q4 = (lane & 7) * 4;
    int rs = rowstart[node];
    int dg = degi[node];
    float4 acc = gather_sum(csr, P1, rs, rs + dg, eg, q4);
    if (lane < 8) {
        float inv = 1.0f / (float)max(dg, 1);
        float4 rr = *(const float4*)&R1[(size_t)node * DIM + q4];
        float4 bb = *(const float4*)&b1[q4];
        float4 v;
        v.x = fmaf(acc.x, inv, rr.x + bb.x);
        v.y = fmaf(acc.y, inv, rr.y + bb.y);
        v.z = fmaf(acc.z, inv, rr.z + bb.z);
        v.w = fmaf(acc.w, inv, rr.w + bb.w);
        v.x = v.x > 0.f ? v.x : 0.f;
        v.y = v.y > 0.f ? v.y : 0.f;
        v.z = v.z > 0.f ? v.z : 0.f;
        v.w = v.w > 0.f ? v.w : 0.f;
        *(float4*)&h[(size_t)node * DIM + q4] = v;
    }
}

// ================= layer-2 aggregate + linear + log_softmax =================
#define NPB2 32   // nodes per block (8 per wave): amortizes the 10KB weight stage

__global__ __launch_bounds__(256)
void agg2_out_kernel(const int* __restrict__ rowstart,
                     const int* __restrict__ degi,
                     const int* __restrict__ csr,
                     const float* __restrict__ h,
                     const float* __restrict__ W2l,
                     const float* __restrict__ W2r,
                     const float* __restrict__ b2,
                     float* __restrict__ out) {
    __shared__ float sW2l[DIM * NC];
    __shared__ float sW2r[DIM * NC];
    __shared__ float sb2[NC];
    for (int i = threadIdx.x; i < DIM * NC; i += 256) {
        sW2l[i] = W2l[i];
        sW2r[i] = W2r[i];
    }
    if (threadIdx.x < NC) sb2[threadIdx.x] = b2[threadIdx.x];
    __syncthreads();

    int lane = threadIdx.x & 63;
    int wv = threadIdx.x >> 6;
    int eg = lane >> 3;
    int q4 = (lane & 7) * 4;
    int nbase = blockIdx.x * NPB2;

    for (int r = 0; r < NPB2 / 4; ++r) {
        int node = nbase + r * 4 + wv;
        if (node >= N_NODES) return;   // no barriers below; per-wave exit is safe
        int rs = rowstart[node];
        int dg = degi[node];
        float4 acc = gather_sum(csr, h, rs, rs + dg, eg, q4);
        float inv = 1.0f / (float)max(dg, 1);
        float a2a[4] = { acc.x * inv, acc.y * inv, acc.z * inv, acc.w * inv };
        float4 hr = *(const float4*)&h[(size_t)node * DIM + q4];
        float hra[4] = { hr.x, hr.y, hr.z, hr.w };

        float y = -INFINITY;
        float sacc = (lane < NC) ? sb2[lane] : 0.f;
#pragma unroll
        for (int k = 0; k < DIM; ++k) {
            float ak = __shfl(a2a[k & 3], k >> 2, 64);
            float hk = __shfl(hra[k & 3], k >> 2, 64);
            if (lane < NC) {
                sacc = fmaf(ak, sW2l[k * NC + lane], sacc);
                sacc = fmaf(hk, sW2r[k * NC + lane], sacc);
            }
        }
        if (lane < NC) y = sacc;
        float m = y;
#pragma unroll
        for (int off = 32; off; off >>= 1) m = fmaxf(m, __shfl_xor(m, off, 64));
        float ex = (lane < NC) ? __expf(y - m) : 0.f;
        float sum = ex;
#pragma unroll
        for (int off = 32; off; off >>= 1) sum += __shfl_xor(sum, off, 64);
        if (lane < NC) out[(size_t)node * NC + lane] = y - m - __logf(sum);
    }
}

// ================= launch =================
extern "C" void kernel_launch(void* const* d_in, const int* in_sizes, int n_in,
                              void* d_out, int out_size, void* d_ws, size_t ws_size,
                              hipStream_t stream) {
    const float* x   = (const float*)d_in[0];
    const int*   ei  = (const int*)d_in[1];   // int32 [2, E]
    const float* W1l = (const float*)d_in[2];
    const float* W1r = (const float*)d_in[3];
    const float* b1  = (const float*)d_in[4];
    const float* W2l = (const float*)d_in[5];
    const float* W2r = (const float*)d_in[6];
    const float* b2  = (const float*)d_in[7];
    float* out = (float*)d_out;

    const int* src = ei;
    const int* dst = ei + N_EDGES;

    char* ws = (char*)d_ws;
    int*   degi     = (int*)ws;                 ws += sizeof(int) * 102400;
    int*   rowstart = (int*)ws;                 ws += sizeof(int) * 102400;
    int*   cursor   = (int*)ws;                 ws += sizeof(int) * 102400;
    int*   counter  = (int*)ws;                 ws += sizeof(int) * 256;
    int*   csr      = (int*)ws;                 ws += sizeof(int) * N_EDGES;
    float* P1       = (float*)ws;               ws += sizeof(float) * N_NODES * DIM;
    float* R1       = (float*)ws;               ws += sizeof(float) * N_NODES * DIM;
    float* h        = (float*)ws;               ws += sizeof(float) * N_NODES * DIM;

    hipMemsetAsync(degi, 0, sizeof(int) * 102400, stream);
    hipMemsetAsync(counter, 0, sizeof(int) * 256, stream);

    deg_kernel<<<(N_EDGES + 255) / 256, 256, 0, stream>>>(dst, degi);
    alloc_kernel<<<(N_NODES + 255) / 256, 256, 0, stream>>>(degi, rowstart, cursor, counter);
    fill_kernel<<<(N_EDGES + 255) / 256, 256, 0, stream>>>(src, dst, cursor, csr);

    proj1_tiled<<<(N_NODES + PT_NODES - 1) / PT_NODES, 256, 0, stream>>>(x, W1l, W1r, P1, R1);

    agg1_h_kernel<<<(N_NODES + 3) / 4, 256, 0, stream>>>(rowstart, degi, csr, P1, R1, b1, h);
    agg2_out_kernel<<<(N_NODES + NPB2 - 1) / NPB2, 256, 0, stream>>>(rowstart, degi, csr, h, W2l, W2r, b2, out);
}

// Round 5
// 479.757 us; speedup vs baseline: 1.8429x; 1.2072x over previous
//
#include <hip/hip_runtime.h>
#include <hip/hip_bf16.h>
#include <math.h>

#define N_NODES 100000
#define N_EDGES 1600000
#define F_IN 256
#define DIM 32
#define NC 40

typedef _Float16 half_t;
union H8 { float4 f4; half_t h[8]; };

// ================= CSR construction =================

__global__ void deg_kernel(const int* __restrict__ dst, int* __restrict__ degi) {
    int i = blockIdx.x * blockDim.x + threadIdx.x;
    if (i < N_EDGES) atomicAdd(&degi[dst[i]], 1);
}

__global__ void alloc_kernel(const int* __restrict__ degi,
                             int* __restrict__ rowstart,
                             int* __restrict__ cursor,
                             int* __restrict__ counter) {
    int i = blockIdx.x * blockDim.x + threadIdx.x;
    int lane = threadIdx.x & 63;
    int v = (i < N_NODES) ? degi[i] : 0;
    int s = v;
#pragma unroll
    for (int off = 1; off < 64; off <<= 1) {
        int t = __shfl_up(s, off, 64);
        if (lane >= off) s += t;
    }
    int base = 0;
    if (lane == 63) base = atomicAdd(counter, s);
    base = __shfl(base, 63, 64);
    if (i < N_NODES) {
        int st = base + s - v;
        rowstart[i] = st;
        cursor[i] = st;
    }
}

__global__ void fill_kernel(const int* __restrict__ src,
                            const int* __restrict__ dst,
                            int* __restrict__ cursor,
                            int* __restrict__ csr) {
    int e = blockIdx.x * blockDim.x + threadIdx.x;
    if (e >= N_EDGES) return;
    int d = dst[e];
    int pos = atomicAdd(&cursor[d], 1);
    csr[pos] = src[e];
}

// ================= layer-1 projection (register-tiled GEMM) =================
// P1 output in fp16; R1 in fp32.
#define PT_NODES 256
#define PT_KT 16

__global__ __launch_bounds__(256)
void proj1_tiled(const float* __restrict__ x,
                 const float* __restrict__ W1l,
                 const float* __restrict__ W1r,
                 half_t* __restrict__ P1h,
                 float* __restrict__ R1) {
    __shared__ float xs[PT_KT][PT_NODES];  // 16 KB
    __shared__ float ws[PT_KT][64];        // 4 KB
    int t = threadIdx.x;
    int ng = t >> 3;   // 0..31 node group
    int cg = t & 7;    // 0..7 col group
    int n0 = blockIdx.x * PT_NODES;

    float acc[8][8];
#pragma unroll
    for (int i = 0; i < 8; ++i)
#pragma unroll
        for (int j = 0; j < 8; ++j) acc[i][j] = 0.f;

    int ldnode = n0 + t; if (ldnode >= N_NODES) ldnode = N_NODES - 1;
    const float* xrow = x + (size_t)ldnode * F_IN;
    int wr = t >> 4;           // 0..15 (k within tile)
    int wc = (t & 15) * 4;     // 0..60

    for (int k0 = 0; k0 < F_IN; k0 += PT_KT) {
        float4 a = *(const float4*)&xrow[k0];
        float4 b = *(const float4*)&xrow[k0 + 4];
        float4 c = *(const float4*)&xrow[k0 + 8];
        float4 d = *(const float4*)&xrow[k0 + 12];
        xs[0][t] = a.x;  xs[1][t] = a.y;  xs[2][t] = a.z;  xs[3][t] = a.w;
        xs[4][t] = b.x;  xs[5][t] = b.y;  xs[6][t] = b.z;  xs[7][t] = b.w;
        xs[8][t] = c.x;  xs[9][t] = c.y;  xs[10][t] = c.z; xs[11][t] = c.w;
        xs[12][t] = d.x; xs[13][t] = d.y; xs[14][t] = d.z; xs[15][t] = d.w;
        float4 w = (wc < 32) ? *(const float4*)&W1l[(size_t)(k0 + wr) * DIM + wc]
                             : *(const float4*)&W1r[(size_t)(k0 + wr) * DIM + (wc - 32)];
        *(float4*)&ws[wr][wc] = w;
        __syncthreads();
#pragma unroll
        for (int kk = 0; kk < PT_KT; ++kk) {
            float xv[8], wv[8];
            *(float4*)&xv[0] = *(const float4*)&xs[kk][ng * 8];
            *(float4*)&xv[4] = *(const float4*)&xs[kk][ng * 8 + 4];
            *(float4*)&wv[0] = *(const float4*)&ws[kk][cg * 8];
            *(float4*)&wv[4] = *(const float4*)&ws[kk][cg * 8 + 4];
#pragma unroll
            for (int i = 0; i < 8; ++i)
#pragma unroll
                for (int j = 0; j < 8; ++j)
                    acc[i][j] = fmaf(xv[i], wv[j], acc[i][j]);
        }
        __syncthreads();
    }

    bool isP = (cg < 4);
    int c0 = (isP ? cg : cg - 4) * 8;
    int nb = n0 + ng * 8;
#pragma unroll
    for (int i = 0; i < 8; ++i) {
        int n = nb + i;
        if (n < N_NODES) {
            if (isP) {
                H8 p;
#pragma unroll
                for (int j = 0; j < 8; ++j) p.h[j] = (half_t)acc[i][j];
                *(float4*)&P1h[(size_t)n * DIM + c0] = p.f4;
            } else {
                *(float4*)&R1[(size_t)n * DIM + c0]     = *(float4*)&acc[i][0];
                *(float4*)&R1[(size_t)n * DIM + c0 + 4] = *(float4*)&acc[i][4];
            }
        }
    }
}

// ================= gather engine =================
// Wave = 16 node-groups x 4 lanes. Lane q of a group owns dims 8q..8q+7 of its
// node and accumulates over the node's whole CSR row. No cross-lane reduction.
__device__ __forceinline__ void gather_node(const int* __restrict__ csr,
                                            const half_t* __restrict__ feat,
                                            int rs, int re, int q8, float acc[8]) {
#pragma unroll
    for (int i = 0; i < 8; ++i) acc[i] = 0.f;
    int e = rs;
    for (; e + 2 <= re; e += 2) {
        int s0 = csr[e];
        int s1 = csr[e + 1];
        H8 u0, u1;
        u0.f4 = *(const float4*)&feat[(size_t)s0 * DIM + q8];
        u1.f4 = *(const float4*)&feat[(size_t)s1 * DIM + q8];
#pragma unroll
        for (int i = 0; i < 8; ++i) acc[i] += (float)u0.h[i] + (float)u1.h[i];
    }
    if (e < re) {
        int s0 = csr[e];
        H8 u0;
        u0.f4 = *(const float4*)&feat[(size_t)s0 * DIM + q8];
#pragma unroll
        for (int i = 0; i < 8; ++i) acc[i] += (float)u0.h[i];
    }
}

// ================= layer-1 aggregate + relu (h in fp16) =================
__global__ __launch_bounds__(256)
void agg1_h_kernel(const int* __restrict__ rowstart,
                   const int* __restrict__ degi,
                   const int* __restrict__ csr,
                   const half_t* __restrict__ P1h,
                   const float* __restrict__ R1,
                   const float* __restrict__ b1,
                   half_t* __restrict__ h) {
    int wave = blockIdx.x * 4 + (threadIdx.x >> 6);
    int lane = threadIdx.x & 63;
    int node = wave * 16 + (lane >> 2);
    if (node >= N_NODES) return;
    int q8 = (lane & 3) * 8;
    int rs = rowstart[node];
    int dg = degi[node];
    float acc[8];
    gather_node(csr, P1h, rs, rs + dg, q8, acc);
    float inv = 1.0f / (float)max(dg, 1);
    float4 r0 = *(const float4*)&R1[(size_t)node * DIM + q8];
    float4 r1 = *(const float4*)&R1[(size_t)node * DIM + q8 + 4];
    float4 bb0 = *(const float4*)&b1[q8];
    float4 bb1 = *(const float4*)&b1[q8 + 4];
    float rb[8] = { r0.x + bb0.x, r0.y + bb0.y, r0.z + bb0.z, r0.w + bb0.w,
                    r1.x + bb1.x, r1.y + bb1.y, r1.z + bb1.z, r1.w + bb1.w };
    H8 o;
#pragma unroll
    for (int i = 0; i < 8; ++i) {
        float v = fmaf(acc[i], inv, rb[i]);
        o.h[i] = (half_t)(v > 0.f ? v : 0.f);
    }
    *(float4*)&h[(size_t)node * DIM + q8] = o.f4;
}

// ================= layer-2 aggregate (a2 in fp16, inv applied) =================
__global__ __launch_bounds__(256)
void agg2_kernel(const int* __restrict__ rowstart,
                 const int* __restrict__ degi,
                 const int* __restrict__ csr,
                 const half_t* __restrict__ h,
                 half_t* __restrict__ a2h) {
    int wave = blockIdx.x * 4 + (threadIdx.x >> 6);
    int lane = threadIdx.x & 63;
    int node = wave * 16 + (lane >> 2);
    if (node >= N_NODES) return;
    int q8 = (lane & 3) * 8;
    int rs = rowstart[node];
    int dg = degi[node];
    float acc[8];
    gather_node(csr, h, rs, rs + dg, q8, acc);
    float inv = 1.0f / (float)max(dg, 1);
    H8 o;
#pragma unroll
    for (int i = 0; i < 8; ++i) o.h[i] = (half_t)(acc[i] * inv);
    *(float4*)&a2h[(size_t)node * DIM + q8] = o.f4;
}

// ================= dense epilogue: out = log_softmax(a2@W2l + h@W2r + b2) ====
// Thread per node; weights staged in LDS (wave-uniform broadcast reads);
// 40 accumulators + softmax fully in registers — zero cross-lane ops.
__global__ __launch_bounds__(256)
void out_dense(const half_t* __restrict__ a2h,
               const half_t* __restrict__ h,
               const float* __restrict__ W2l,
               const float* __restrict__ W2r,
               const float* __restrict__ b2,
               float* __restrict__ out) {
    __shared__ float sWl[DIM * NC];
    __shared__ float sWr[DIM * NC];
    __shared__ float sb[NC];
    for (int i = threadIdx.x; i < DIM * NC; i += 256) {
        sWl[i] = W2l[i];
        sWr[i] = W2r[i];
    }
    if (threadIdx.x < NC) sb[threadIdx.x] = b2[threadIdx.x];
    __syncthreads();

    int n = blockIdx.x * 256 + threadIdx.x;
    if (n >= N_NODES) return;

    float av[32], hv[32];
#pragma unroll
    for (int c = 0; c < 4; ++c) {
        H8 ua, uh;
        ua.f4 = *(const float4*)&a2h[(size_t)n * DIM + c * 8];
        uh.f4 = *(const float4*)&h[(size_t)n * DIM + c * 8];
#pragma unroll
        for (int i = 0; i < 8; ++i) {
            av[c * 8 + i] = (float)ua.h[i];
            hv[c * 8 + i] = (float)uh.h[i];
        }
    }

    float acc[NC];
#pragma unroll
    for (int c = 0; c < NC; ++c) acc[c] = sb[c];
#pragma unroll
    for (int k = 0; k < DIM; ++k) {
        float a = av[k], hh = hv[k];
#pragma unroll
        for (int c = 0; c < NC; ++c)
            acc[c] = fmaf(a, sWl[k * NC + c], fmaf(hh, sWr[k * NC + c], acc[c]));
    }

    float m = acc[0];
#pragma unroll
    for (int c = 1; c < NC; ++c) m = fmaxf(m, acc[c]);
    float s = 0.f;
#pragma unroll
    for (int c = 0; c < NC; ++c) s += __expf(acc[c] - m);
    float lg = m + __logf(s);
    float* orow = out + (size_t)n * NC;
#pragma unroll
    for (int c4 = 0; c4 < NC / 4; ++c4) {
        float4 v = make_float4(acc[c4 * 4] - lg, acc[c4 * 4 + 1] - lg,
                               acc[c4 * 4 + 2] - lg, acc[c4 * 4 + 3] - lg);
        *(float4*)&orow[c4 * 4] = v;
    }
}

// ================= launch =================
extern "C" void kernel_launch(void* const* d_in, const int* in_sizes, int n_in,
                              void* d_out, int out_size, void* d_ws, size_t ws_size,
                              hipStream_t stream) {
    const float* x   = (const float*)d_in[0];
    const int*   ei  = (const int*)d_in[1];   // int32 [2, E]
    const float* W1l = (const float*)d_in[2];
    const float* W1r = (const float*)d_in[3];
    const float* b1  = (const float*)d_in[4];
    const float* W2l = (const float*)d_in[5];
    const float* W2r = (const float*)d_in[6];
    const float* b2  = (const float*)d_in[7];
    float* out = (float*)d_out;

    const int* src = ei;
    const int* dst = ei + N_EDGES;

    char* ws = (char*)d_ws;
    int*    degi     = (int*)ws;      ws += sizeof(int) * 102400;
    int*    counter  = (int*)ws;      ws += sizeof(int) * 256;
    int*    rowstart = (int*)ws;      ws += sizeof(int) * 102400;
    int*    cursor   = (int*)ws;      ws += sizeof(int) * 102400;
    int*    csr      = (int*)ws;      ws += sizeof(int) * N_EDGES;
    half_t* P1h      = (half_t*)ws;   ws += sizeof(half_t) * N_NODES * DIM;
    half_t* h        = (half_t*)ws;   ws += sizeof(half_t) * N_NODES * DIM;
    half_t* a2h      = (half_t*)ws;   ws += sizeof(half_t) * N_NODES * DIM;
    float*  R1       = (float*)ws;    ws += sizeof(float) * N_NODES * DIM;

    hipMemsetAsync(degi, 0, sizeof(int) * (102400 + 256), stream);  // degi + counter

    deg_kernel<<<(N_EDGES + 255) / 256, 256, 0, stream>>>(dst, degi);
    alloc_kernel<<<(N_NODES + 255) / 256, 256, 0, stream>>>(degi, rowstart, cursor, counter);
    fill_kernel<<<(N_EDGES + 255) / 256, 256, 0, stream>>>(src, dst, cursor, csr);

    proj1_tiled<<<(N_NODES + PT_NODES - 1) / PT_NODES, 256, 0, stream>>>(x, W1l, W1r, P1h, R1);

    int gather_blocks = (N_NODES + 63) / 64;   // 4 waves/block * 16 nodes/wave
    agg1_h_kernel<<<gather_blocks, 256, 0, stream>>>(rowstart, degi, csr, P1h, R1, b1, h);
    agg2_kernel<<<gather_blocks, 256, 0, stream>>>(rowstart, degi, csr, h, a2h);
    out_dense<<<(N_NODES + 255) / 256, 256, 0, stream>>>(a2h, h, W2l, W2r, b2, out);
}